// Round 1
// baseline (261.824 us; speedup 1.0000x reference)
//
#include <hip/hip_runtime.h>

// Problem constants (from reference setup_inputs)
static constexpr int B = 32;
static constexpr int P = 19248;
static constexpr int G = 32;
static constexpr int C = 41;          // num classes
static constexpr float POS_TH = 0.5f;
static constexpr float NEG_TH = 0.4f;

static constexpr int PB = (P + 255) / 256;   // 76 prior-tiles

__device__ __forceinline__ float sl1(float d) {
    d = fabsf(d);
    return d < 1.0f ? 0.5f * d * d : d - 0.5f;
}

// ---------------------------------------------------------------------------
// Kernel 1: per (b,p) best gt (max/argmax IoU over G). First-max tie-break.
// ---------------------------------------------------------------------------
__global__ __launch_bounds__(256) void k_best_truth(
    const float* __restrict__ priors, const float* __restrict__ gt,
    float* __restrict__ bt_ov, int* __restrict__ bt_idx) {
    int b = blockIdx.y;
    int p = blockIdx.x * 256 + threadIdx.x;
    __shared__ float4 sg[G];
    __shared__ float sarea[G];
    if (threadIdx.x < G) {
        float4 g4 = reinterpret_cast<const float4*>(gt)[b * G + threadIdx.x];
        sg[threadIdx.x] = g4;
        sarea[threadIdx.x] = (g4.z - g4.x) * (g4.w - g4.y);
    }
    __syncthreads();
    if (p >= P) return;
    float4 pr = reinterpret_cast<const float4*>(priors)[p];
    float px1 = pr.x - pr.z * 0.5f, py1 = pr.y - pr.w * 0.5f;
    float px2 = pr.x + pr.z * 0.5f, py2 = pr.y + pr.w * 0.5f;
    float parea = (px2 - px1) * (py2 - py1);
    float best = -1.0f; int bidx = 0;
#pragma unroll
    for (int g = 0; g < G; ++g) {
        float4 gb = sg[g];
        float lx = fmaxf(gb.x, px1), ly = fmaxf(gb.y, py1);
        float rx = fminf(gb.z, px2), ry = fminf(gb.w, py2);
        float w = fmaxf(rx - lx, 0.0f), h = fmaxf(ry - ly, 0.0f);
        float inter = w * h;
        float iou = inter / (sarea[g] + parea - inter);
        if (iou > best) { best = iou; bidx = g; }   // strict > keeps FIRST max (jnp.argmax)
    }
    bt_ov[b * P + p] = best;
    bt_idx[b * P + p] = bidx;
}

// ---------------------------------------------------------------------------
// Kernel 1b: per (b,g) best prior (argmax IoU over P). One block per (b,g).
// Tie-break: smaller p wins (jnp.argmax first occurrence).
// ---------------------------------------------------------------------------
__global__ __launch_bounds__(256) void k_best_prior(
    const float* __restrict__ priors, const float* __restrict__ gt,
    int* __restrict__ bp_idx) {
    int g = blockIdx.x, b = blockIdx.y;
    float4 gb = reinterpret_cast<const float4*>(gt)[b * G + g];
    float ga = (gb.z - gb.x) * (gb.w - gb.y);
    float best = -1.0f; int bidx = 0;
    for (int p = threadIdx.x; p < P; p += 256) {
        float4 pr = reinterpret_cast<const float4*>(priors)[p];
        float px1 = pr.x - pr.z * 0.5f, py1 = pr.y - pr.w * 0.5f;
        float px2 = pr.x + pr.z * 0.5f, py2 = pr.y + pr.w * 0.5f;
        float parea = (px2 - px1) * (py2 - py1);
        float lx = fmaxf(gb.x, px1), ly = fmaxf(gb.y, py1);
        float rx = fminf(gb.z, px2), ry = fminf(gb.w, py2);
        float w = fmaxf(rx - lx, 0.0f), h = fmaxf(ry - ly, 0.0f);
        float inter = w * h;
        float iou = inter / (ga + parea - inter);
        if (iou > best) { best = iou; bidx = p; }   // ascending p per thread -> first max
    }
#pragma unroll
    for (int d = 32; d; d >>= 1) {
        float ov = __shfl_xor(best, d);
        int   oi = __shfl_xor(bidx, d);
        if (ov > best || (ov == best && oi < bidx)) { best = ov; bidx = oi; }
    }
    __shared__ float sv[4]; __shared__ int si[4];
    int wid = threadIdx.x >> 6, lane = threadIdx.x & 63;
    if (lane == 0) { sv[wid] = best; si[wid] = bidx; }
    __syncthreads();
    if (threadIdx.x == 0) {
#pragma unroll
        for (int w = 1; w < 4; ++w)
            if (sv[w] > best || (sv[w] == best && si[w] < bidx)) { best = sv[w]; bidx = si[w]; }
        bp_idx[b * G + g] = bidx;
    }
}

// ---------------------------------------------------------------------------
// Kernel 2: force each gt to keep its best prior (sequential per batch:
// later g wins on duplicate priors, matching the loop semantics).
// ---------------------------------------------------------------------------
__global__ void k_force(const int* __restrict__ bp_idx,
                        float* __restrict__ bt_ov, int* __restrict__ bt_idx) {
    int b = blockIdx.x * blockDim.x + threadIdx.x;
    if (b >= B) return;
    for (int g = 0; g < G; ++g) {
        int p = bp_idx[b * G + g];
        bt_ov[b * P + p] = 2.0f;
        bt_idx[b * P + p] = g;
    }
}

// ---------------------------------------------------------------------------
// Kernel 3: main streaming kernel. Per (b,p): conf target, box loss for
// positives, CE loss (LSE - picked), mined value. Block-reduced atomics.
// conf_data staged through LDS with coalesced dword loads (rows are 164 B,
// not 16B-aligned, so no global float4).
// ---------------------------------------------------------------------------
__global__ __launch_bounds__(256) void k_main(
    const float* __restrict__ loc_data, const float* __restrict__ conf_data,
    const float* __restrict__ priors, const float* __restrict__ gt,
    const int* __restrict__ labels,
    const float* __restrict__ bt_ov, const int* __restrict__ bt_idx,
    float* __restrict__ mined,
    int* __restrict__ npos_b, int* __restrict__ npos_tot,
    float* __restrict__ box_sum, float* __restrict__ posc_sum) {
    int b = blockIdx.y;
    int p0 = blockIdx.x * 256;
    int p = p0 + threadIdx.x;
    __shared__ float sconf[256 * C];
    int valid = min(256, P - p0);
    size_t gbase = ((size_t)b * P + p0) * C;
    int tot = valid * C;
    for (int i = threadIdx.x; i < tot; i += 256)
        sconf[i] = conf_data[gbase + i];
    __syncthreads();

    float my_box = 0.0f, my_posc = 0.0f; int my_pos = 0;
    if (p < P) {
        float ov = bt_ov[b * P + p];
        int cls = 0;
        bool pos = false, neutral = false;
        float boxl = 0.0f;
        if (ov >= POS_TH) {
            pos = true;
            int g = bt_idx[b * P + p];
            cls = labels[b * G + g] + 1;
            float4 gb = reinterpret_cast<const float4*>(gt)[b * G + g];
            float4 pr = reinterpret_cast<const float4*>(priors)[p];
            float mcx = (gb.x + gb.z) * 0.5f, mcy = (gb.y + gb.w) * 0.5f;
            float tx = (mcx - pr.x) / (0.1f * pr.z);
            float ty = (mcy - pr.y) / (0.1f * pr.w);
            float tw = __logf(fmaxf((gb.z - gb.x) / pr.z, 1e-8f)) / 0.2f;
            float th = __logf(fmaxf((gb.w - gb.y) / pr.w, 1e-8f)) / 0.2f;
            float4 ld = reinterpret_cast<const float4*>(loc_data)[b * P + p];
            boxl = sl1(ld.x - tx) + sl1(ld.y - ty) + sl1(ld.z - tw) + sl1(ld.w - th);
        } else if (ov >= NEG_TH) {
            neutral = true;
        }
        const float* cv = &sconf[threadIdx.x * C];
        float mx = cv[0];
#pragma unroll
        for (int c = 1; c < C; ++c) mx = fmaxf(mx, cv[c]);
        float se = 0.0f;
#pragma unroll
        for (int c = 0; c < C; ++c) se += __expf(cv[c] - mx);
        float lse = mx + __logf(se);
        float lc = lse - cv[cls];          // >= 0 always (lse >= mx >= picked)
        mined[(size_t)b * P + p] = (pos || neutral) ? 0.0f : lc;
        my_pos = pos ? 1 : 0;
        my_box = boxl;
        my_posc = pos ? lc : 0.0f;
    }

    // block reduction: 2 floats + 1 int
#pragma unroll
    for (int d = 32; d; d >>= 1) {
        my_box  += __shfl_xor(my_box, d);
        my_posc += __shfl_xor(my_posc, d);
        my_pos  += __shfl_xor(my_pos, d);
    }
    __shared__ float rb[4], rc[4]; __shared__ int rp[4];
    int wid = threadIdx.x >> 6, lane = threadIdx.x & 63;
    if (lane == 0) { rb[wid] = my_box; rc[wid] = my_posc; rp[wid] = my_pos; }
    __syncthreads();
    if (threadIdx.x == 0) {
        float sb = rb[0] + rb[1] + rb[2] + rb[3];
        float sc = rc[0] + rc[1] + rc[2] + rc[3];
        int   sp = rp[0] + rp[1] + rp[2] + rp[3];
        if (sp) { atomicAdd(&npos_b[b], sp); atomicAdd(npos_tot, sp); }
        atomicAdd(box_sum, sb);
        atomicAdd(posc_sum, sc);
    }
}

// ---------------------------------------------------------------------------
// Kernel 4: per batch, sum of top-k of mined (k = min(3*npos_b, P-1)).
// Exact k-th largest via 4-level radix select on float bits (all mined >= 0,
// so uint ordering == float ordering). Tie handling is exact by construction.
// ---------------------------------------------------------------------------
__global__ __launch_bounds__(256) void k_topk(
    const float* __restrict__ mined, const int* __restrict__ npos_b,
    float* __restrict__ neg_sum) {
    int b = blockIdx.x;
    const float* mb = mined + (size_t)b * P;
    int np = npos_b[b];
    int k = 3 * np; if (k > P - 1) k = P - 1;
    if (k <= 0) return;

    __shared__ unsigned hist[256];
    __shared__ unsigned sb[3];   // [0]=prefix, [1]=want, [2]=cnt_gt
    if (threadIdx.x == 0) { sb[0] = 0u; sb[1] = (unsigned)k; sb[2] = 0u; }
    __syncthreads();

#pragma unroll
    for (int level = 0; level < 4; ++level) {
        int shift = 24 - 8 * level;
        hist[threadIdx.x] = 0u;
        __syncthreads();
        unsigned pref = sb[0];
        unsigned pmask = level ? (0xFFFFFFFFu << (shift + 8)) : 0u;
        for (int i = threadIdx.x; i < P; i += 256) {
            unsigned v = __float_as_uint(mb[i]);
            if ((v & pmask) == pref)
                atomicAdd(&hist[(v >> shift) & 0xFFu], 1u);
        }
        __syncthreads();
        if (threadIdx.x == 0) {
            unsigned want = sb[1], cum = 0u; int bsel = 0;
            for (int bb = 255; bb >= 0; --bb) {
                unsigned h = hist[bb];
                if (cum + h >= want) { bsel = bb; break; }
                cum += h;
            }
            sb[0] = pref | ((unsigned)bsel << shift);
            sb[1] = want - cum;
            sb[2] += cum;
        }
        __syncthreads();
    }
    unsigned vk = sb[0];
    unsigned cnt_gt = sb[2];
    float vkf = __uint_as_float(vk);

    float ssum = 0.0f;
    for (int i = threadIdx.x; i < P; i += 256) {
        float x = mb[i];
        if (__float_as_uint(x) > vk) ssum += x;
    }
#pragma unroll
    for (int d = 32; d; d >>= 1) ssum += __shfl_xor(ssum, d);
    __shared__ float rs[4];
    int wid = threadIdx.x >> 6, lane = threadIdx.x & 63;
    if (lane == 0) rs[wid] = ssum;
    __syncthreads();
    if (threadIdx.x == 0) {
        float tot = rs[0] + rs[1] + rs[2] + rs[3]
                  + (float)(k - (int)cnt_gt) * vkf;
        atomicAdd(neg_sum, tot);
    }
}

// ---------------------------------------------------------------------------
// Kernel 5: finalize scalar loss.
// ---------------------------------------------------------------------------
__global__ void k_final(const int* __restrict__ npos_tot,
                        const float* __restrict__ box_sum,
                        const float* __restrict__ posc_sum,
                        const float* __restrict__ neg_sum,
                        float* __restrict__ out) {
    if (threadIdx.x == 0) {
        float np = fmaxf((float)(*npos_tot), 1.0f);
        out[0] = (*box_sum) / np * 1.5f + ((*posc_sum) + (*neg_sum)) / np * 6.5f;
    }
}

extern "C" void kernel_launch(void* const* d_in, const int* in_sizes, int n_in,
                              void* d_out, int out_size, void* d_ws, size_t ws_size,
                              hipStream_t stream) {
    const float* loc    = (const float*)d_in[0];
    const float* conf   = (const float*)d_in[1];
    const float* priors = (const float*)d_in[2];
    const float* gt     = (const float*)d_in[3];
    const int*   labels = (const int*)d_in[4];
    float* out = (float*)d_out;

    char* w = (char*)d_ws;
    float* bt_ov  = (float*)w;  w += sizeof(float) * B * P;
    int*   bt_idx = (int*)w;    w += sizeof(int)   * B * P;
    float* mined  = (float*)w;  w += sizeof(float) * B * P;
    int*   bp     = (int*)w;    w += sizeof(int)   * B * G;
    int*   npb    = (int*)w;    w += sizeof(int)   * B;
    int*   npt    = (int*)w;    w += sizeof(int);
    float* bsum   = (float*)w;  w += sizeof(float);
    float* pcsum  = (float*)w;  w += sizeof(float);
    float* nsum   = (float*)w;  w += sizeof(float);

    // zero the accumulators (npb..nsum are contiguous)
    hipMemsetAsync(npb, 0, sizeof(int) * (B + 1) + sizeof(float) * 3, stream);

    dim3 gridP(PB, B);
    k_best_truth<<<gridP, 256, 0, stream>>>(priors, gt, bt_ov, bt_idx);
    k_best_prior<<<dim3(G, B), 256, 0, stream>>>(priors, gt, bp);
    k_force<<<1, 64, 0, stream>>>(bp, bt_ov, bt_idx);
    k_main<<<gridP, 256, 0, stream>>>(loc, conf, priors, gt, labels,
                                      bt_ov, bt_idx, mined,
                                      npb, npt, bsum, pcsum);
    k_topk<<<B, 256, 0, stream>>>(mined, npb, nsum);
    k_final<<<1, 64, 0, stream>>>(npt, bsum, pcsum, nsum, out);
}

// Round 2
// 215.479 us; speedup vs baseline: 1.2151x; 1.2151x over previous
//
#include <hip/hip_runtime.h>

// Problem constants (from reference setup_inputs)
static constexpr int B = 32;
static constexpr int P = 19248;
static constexpr int G = 32;
static constexpr int C = 41;          // num classes
static constexpr float POS_TH = 0.5f;
static constexpr float NEG_TH = 0.4f;

static constexpr int PB = (P + 255) / 256;   // 76 prior-tiles

__device__ __forceinline__ float sl1(float d) {
    d = fabsf(d);
    return d < 1.0f ? 0.5f * d * d : d - 0.5f;
}

// ---------------------------------------------------------------------------
// Kernel 1: fused match. Per (b,p): best gt (max/argmax IoU over G, first-max
// tie-break). Simultaneously per (b,g): argmax over p via wave reduce +
// packed-u64 global atomicMax ((iou_bits<<32)|(~p) -> higher IoU, then
// smaller p wins). Block (0,0) also zeroes the scalar accumulators (safe:
// k_main only reads them after this whole grid completes).
// ---------------------------------------------------------------------------
__global__ __launch_bounds__(256) void k_match(
    const float* __restrict__ priors, const float* __restrict__ gt,
    float* __restrict__ bt_ov, int* __restrict__ bt_idx,
    unsigned long long* __restrict__ bp_max,
    int* __restrict__ npos_b, int* __restrict__ npos_tot,
    float* __restrict__ box_sum, float* __restrict__ posc_sum,
    float* __restrict__ neg_sum) {
    int b = blockIdx.y;
    int p0 = blockIdx.x * 256;
    int p = p0 + threadIdx.x;
    __shared__ float4 sg[G];
    __shared__ float sarea[G];
    __shared__ unsigned long long swave[G][4];

    if (blockIdx.x == 0 && b == 0) {        // zero accumulators once per call
        if (threadIdx.x < B) npos_b[threadIdx.x] = 0;
        if (threadIdx.x == B) *npos_tot = 0;
        if (threadIdx.x == B + 1) *box_sum = 0.0f;
        if (threadIdx.x == B + 2) *posc_sum = 0.0f;
        if (threadIdx.x == B + 3) *neg_sum = 0.0f;
    }
    if (threadIdx.x < G) {
        float4 g4 = reinterpret_cast<const float4*>(gt)[b * G + threadIdx.x];
        sg[threadIdx.x] = g4;
        sarea[threadIdx.x] = (g4.z - g4.x) * (g4.w - g4.y);
    }
    __syncthreads();

    bool valid = (p < P);
    float px1 = 0, py1 = 0, px2 = 0, py2 = 0, parea = 0;
    if (valid) {
        float4 pr = reinterpret_cast<const float4*>(priors)[p];
        px1 = pr.x - pr.z * 0.5f; py1 = pr.y - pr.w * 0.5f;
        px2 = pr.x + pr.z * 0.5f; py2 = pr.y + pr.w * 0.5f;
        parea = (px2 - px1) * (py2 - py1);
    }
    float ious[G];
    float best = -1.0f; int bidx = 0;
#pragma unroll
    for (int g = 0; g < G; ++g) {
        float iou = -1.0f;
        if (valid) {
            float4 gb = sg[g];
            float lx = fmaxf(gb.x, px1), ly = fmaxf(gb.y, py1);
            float rx = fminf(gb.z, px2), ry = fminf(gb.w, py2);
            float w = fmaxf(rx - lx, 0.0f), h = fmaxf(ry - ly, 0.0f);
            float inter = w * h;
            iou = inter / (sarea[g] + parea - inter);
        }
        ious[g] = iou;
        if (iou > best) { best = iou; bidx = g; }   // strict > keeps FIRST g
    }
    if (valid) {
        bt_ov[b * P + p] = best;
        bt_idx[b * P + p] = bidx;
    }

    // per-g argmax over this block's 256 priors
    int lane = threadIdx.x & 63, wid = threadIdx.x >> 6;
#pragma unroll
    for (int g = 0; g < G; ++g) {
        float v = ious[g];
        float m = v;
#pragma unroll
        for (int d = 32; d; d >>= 1) m = fmaxf(m, __shfl_xor(m, d));
        unsigned long long mask = __ballot(v == m);  // invalid lanes: v=-1 < m
        if (lane == 0) {
            unsigned long long pk = 0ull;
            if (m >= 0.0f) {
                int src = __ffsll(mask) - 1;          // lowest lane = smallest p
                int pw = p0 + wid * 64 + src;
                pk = ((unsigned long long)__float_as_uint(m) << 32)
                   | (unsigned)(0xFFFFFFFFu - (unsigned)pw);
            }
            swave[g][wid] = pk;
        }
    }
    __syncthreads();
    if (threadIdx.x < G) {
        int g = threadIdx.x;
        unsigned long long mx = swave[g][0];
        mx = swave[g][1] > mx ? swave[g][1] : mx;
        mx = swave[g][2] > mx ? swave[g][2] : mx;
        mx = swave[g][3] > mx ? swave[g][3] : mx;
        atomicMax(&bp_max[b * G + g], mx);
    }
}

// ---------------------------------------------------------------------------
// Kernel 2: main streaming kernel. Per (b,p): conf target (with forced-prior
// override checked inline against the 32 per-batch winners), box loss for
// positives, CE loss (LSE - picked), mined value. conf staged via float4
// (block slab is 16B-aligned, size divisible by 16).
// ---------------------------------------------------------------------------
__global__ __launch_bounds__(256) void k_main(
    const float* __restrict__ loc_data, const float* __restrict__ conf_data,
    const float* __restrict__ priors, const float* __restrict__ gt,
    const int* __restrict__ labels,
    const float* __restrict__ bt_ov, const int* __restrict__ bt_idx,
    const unsigned long long* __restrict__ bp_max,
    float* __restrict__ mined,
    int* __restrict__ npos_b, int* __restrict__ npos_tot,
    float* __restrict__ box_sum, float* __restrict__ posc_sum) {
    int b = blockIdx.y;
    int p0 = blockIdx.x * 256;
    int p = p0 + threadIdx.x;
    __shared__ float sconf[256 * C];
    __shared__ int sforce[G];
    if (threadIdx.x < G)
        sforce[threadIdx.x] = (int)(0xFFFFFFFFu - (unsigned)bp_max[b * G + threadIdx.x]);
    int valid = min(256, P - p0);
    size_t gbase = ((size_t)b * P + p0) * C;
    int tot4 = (valid * C) >> 2;          // always exact (256*41, 48*41 both %4==0)
    const float4* g4 = reinterpret_cast<const float4*>(conf_data + gbase);
    float4* s4 = reinterpret_cast<float4*>(sconf);
    for (int i = threadIdx.x; i < tot4; i += 256) s4[i] = g4[i];
    __syncthreads();

    float my_box = 0.0f, my_posc = 0.0f; int my_pos = 0;
    if (p < P) {
        float ov = bt_ov[b * P + p];
        int fidx = -1;
#pragma unroll
        for (int g = 0; g < G; ++g)
            if (p == sforce[g]) fidx = g;             // ascending g: LAST wins
        bool pos = false, neutral = false;
        int gidx = 0, cls = 0;
        float boxl = 0.0f;
        if (fidx >= 0)            { pos = true; gidx = fidx; }
        else if (ov >= POS_TH)    { pos = true; gidx = bt_idx[b * P + p]; }
        else if (ov >= NEG_TH)    { neutral = true; }
        if (pos) {
            cls = labels[b * G + gidx] + 1;
            float4 gb = reinterpret_cast<const float4*>(gt)[b * G + gidx];
            float4 pr = reinterpret_cast<const float4*>(priors)[p];
            float mcx = (gb.x + gb.z) * 0.5f, mcy = (gb.y + gb.w) * 0.5f;
            float tx = (mcx - pr.x) / (0.1f * pr.z);
            float ty = (mcy - pr.y) / (0.1f * pr.w);
            float tw = __logf(fmaxf((gb.z - gb.x) / pr.z, 1e-8f)) / 0.2f;
            float th = __logf(fmaxf((gb.w - gb.y) / pr.w, 1e-8f)) / 0.2f;
            float4 ld = reinterpret_cast<const float4*>(loc_data)[b * P + p];
            boxl = sl1(ld.x - tx) + sl1(ld.y - ty) + sl1(ld.z - tw) + sl1(ld.w - th);
        }
        const float* cv = &sconf[threadIdx.x * C];
        float mx = cv[0];
#pragma unroll
        for (int c = 1; c < C; ++c) mx = fmaxf(mx, cv[c]);
        float se = 0.0f;
#pragma unroll
        for (int c = 0; c < C; ++c) se += __expf(cv[c] - mx);
        float lse = mx + __logf(se);
        float lc = lse - cv[cls];          // >= 0 always (lse >= mx >= picked)
        mined[(size_t)b * P + p] = (pos || neutral) ? 0.0f : lc;
        my_pos = pos ? 1 : 0;
        my_box = boxl;
        my_posc = pos ? lc : 0.0f;
    }

#pragma unroll
    for (int d = 32; d; d >>= 1) {
        my_box  += __shfl_xor(my_box, d);
        my_posc += __shfl_xor(my_posc, d);
        my_pos  += __shfl_xor(my_pos, d);
    }
    __shared__ float rb[4], rc[4]; __shared__ int rp[4];
    int wid = threadIdx.x >> 6, lane = threadIdx.x & 63;
    if (lane == 0) { rb[wid] = my_box; rc[wid] = my_posc; rp[wid] = my_pos; }
    __syncthreads();
    if (threadIdx.x == 0) {
        float sb = rb[0] + rb[1] + rb[2] + rb[3];
        float sc = rc[0] + rc[1] + rc[2] + rc[3];
        int   sp = rp[0] + rp[1] + rp[2] + rp[3];
        if (sp) { atomicAdd(&npos_b[b], sp); atomicAdd(npos_tot, sp); }
        atomicAdd(box_sum, sb);
        atomicAdd(posc_sum, sc);
    }
}

// ---------------------------------------------------------------------------
// Kernel 3: per batch, sum of top-k of mined (k = min(3*npos_b, P-1)).
// Exact k-th largest via 4-level radix select on float bits (all mined >= 0).
// 1024 threads to cut the latency-bound pass count.
// ---------------------------------------------------------------------------
__global__ __launch_bounds__(1024) void k_topk(
    const float* __restrict__ mined, const int* __restrict__ npos_b,
    float* __restrict__ neg_sum) {
    int b = blockIdx.x;
    const float* mb = mined + (size_t)b * P;
    int np = npos_b[b];
    int k = 3 * np; if (k > P - 1) k = P - 1;
    if (k <= 0) return;

    __shared__ unsigned hist[256];
    __shared__ unsigned sb[3];   // [0]=prefix, [1]=want, [2]=cnt_gt
    if (threadIdx.x == 0) { sb[0] = 0u; sb[1] = (unsigned)k; sb[2] = 0u; }
    __syncthreads();

#pragma unroll
    for (int level = 0; level < 4; ++level) {
        int shift = 24 - 8 * level;
        if (threadIdx.x < 256) hist[threadIdx.x] = 0u;
        __syncthreads();
        unsigned pref = sb[0];
        unsigned pmask = level ? (0xFFFFFFFFu << (shift + 8)) : 0u;
        for (int i = threadIdx.x; i < P; i += 1024) {
            unsigned v = __float_as_uint(mb[i]);
            if ((v & pmask) == pref)
                atomicAdd(&hist[(v >> shift) & 0xFFu], 1u);
        }
        __syncthreads();
        if (threadIdx.x == 0) {
            unsigned want = sb[1], cum = 0u; int bsel = 0;
            for (int bb = 255; bb >= 0; --bb) {
                unsigned h = hist[bb];
                if (cum + h >= want) { bsel = bb; break; }
                cum += h;
            }
            sb[0] = pref | ((unsigned)bsel << shift);
            sb[1] = want - cum;
            sb[2] += cum;
        }
        __syncthreads();
    }
    unsigned vk = sb[0];
    unsigned cnt_gt = sb[2];
    float vkf = __uint_as_float(vk);

    float ssum = 0.0f;
    for (int i = threadIdx.x; i < P; i += 1024) {
        float x = mb[i];
        if (__float_as_uint(x) > vk) ssum += x;
    }
#pragma unroll
    for (int d = 32; d; d >>= 1) ssum += __shfl_xor(ssum, d);
    __shared__ float rs[16];
    int wid = threadIdx.x >> 6, lane = threadIdx.x & 63;
    if (lane == 0) rs[wid] = ssum;
    __syncthreads();
    if (threadIdx.x == 0) {
        float tot = 0.0f;
#pragma unroll
        for (int w = 0; w < 16; ++w) tot += rs[w];
        tot += (float)(k - (int)cnt_gt) * vkf;
        atomicAdd(neg_sum, tot);
    }
}

// ---------------------------------------------------------------------------
// Kernel 4: finalize scalar loss.
// ---------------------------------------------------------------------------
__global__ void k_final(const int* __restrict__ npos_tot,
                        const float* __restrict__ box_sum,
                        const float* __restrict__ posc_sum,
                        const float* __restrict__ neg_sum,
                        float* __restrict__ out) {
    if (threadIdx.x == 0) {
        float np = fmaxf((float)(*npos_tot), 1.0f);
        out[0] = (*box_sum) / np * 1.5f + ((*posc_sum) + (*neg_sum)) / np * 6.5f;
    }
}

extern "C" void kernel_launch(void* const* d_in, const int* in_sizes, int n_in,
                              void* d_out, int out_size, void* d_ws, size_t ws_size,
                              hipStream_t stream) {
    const float* loc    = (const float*)d_in[0];
    const float* conf   = (const float*)d_in[1];
    const float* priors = (const float*)d_in[2];
    const float* gt     = (const float*)d_in[3];
    const int*   labels = (const int*)d_in[4];
    float* out = (float*)d_out;

    char* w = (char*)d_ws;
    float* bt_ov  = (float*)w;  w += sizeof(float) * B * P;
    int*   bt_idx = (int*)w;    w += sizeof(int)   * B * P;
    float* mined  = (float*)w;  w += sizeof(float) * B * P;
    unsigned long long* bp = (unsigned long long*)w; w += sizeof(unsigned long long) * B * G;
    int*   npb    = (int*)w;    w += sizeof(int)   * B;
    int*   npt    = (int*)w;    w += sizeof(int);
    float* bsum   = (float*)w;  w += sizeof(float);
    float* pcsum  = (float*)w;  w += sizeof(float);
    float* nsum   = (float*)w;  w += sizeof(float);

    // bp_max must be zero BEFORE k_match's atomics; everything else is zeroed
    // inside k_match block (0,0).
    hipMemsetAsync(bp, 0, sizeof(unsigned long long) * B * G, stream);

    dim3 gridP(PB, B);
    k_match<<<gridP, 256, 0, stream>>>(priors, gt, bt_ov, bt_idx, bp,
                                       npb, npt, bsum, pcsum, nsum);
    k_main<<<gridP, 256, 0, stream>>>(loc, conf, priors, gt, labels,
                                      bt_ov, bt_idx, bp, mined,
                                      npb, npt, bsum, pcsum);
    k_topk<<<B, 1024, 0, stream>>>(mined, npb, nsum);
    k_final<<<1, 64, 0, stream>>>(npt, bsum, pcsum, nsum, out);
}

// Round 3
// 139.867 us; speedup vs baseline: 1.8720x; 1.5406x over previous
//
#include <hip/hip_runtime.h>

// Problem constants (from reference setup_inputs)
static constexpr int B = 32;
static constexpr int P = 19248;
static constexpr int G = 32;
static constexpr int C = 41;          // num classes
static constexpr float POS_TH = 0.5f;
static constexpr float NEG_TH = 0.4f;

static constexpr int PB = (P + 255) / 256;   // 76 prior-tiles

__device__ __forceinline__ float sl1(float d) {
    d = fabsf(d);
    return d < 1.0f ? 0.5f * d * d : d - 0.5f;
}

// ---------------------------------------------------------------------------
// Kernel 1: fused match. Per (b,p): best gt (max/argmax IoU over G, first-max
// tie-break). Simultaneously per (b,g): argmax over p via wave reduce +
// packed-u64 global atomicMax ((iou_bits<<32)|(~p) -> higher IoU, then
// smaller p wins). atomicMax targets are 1024 DISTINCT addresses (76 blocks
// each) — low contention, unlike the old same-address scalar atomics.
// ---------------------------------------------------------------------------
__global__ __launch_bounds__(256) void k_match(
    const float* __restrict__ priors, const float* __restrict__ gt,
    float* __restrict__ bt_ov, int* __restrict__ bt_idx,
    unsigned long long* __restrict__ bp_max) {
    int b = blockIdx.y;
    int p0 = blockIdx.x * 256;
    int p = p0 + threadIdx.x;
    __shared__ float4 sg[G];
    __shared__ float sarea[G];
    __shared__ unsigned long long swave[G][4];

    if (threadIdx.x < G) {
        float4 g4 = reinterpret_cast<const float4*>(gt)[b * G + threadIdx.x];
        sg[threadIdx.x] = g4;
        sarea[threadIdx.x] = (g4.z - g4.x) * (g4.w - g4.y);
    }
    __syncthreads();

    bool valid = (p < P);
    float px1 = 0, py1 = 0, px2 = 0, py2 = 0, parea = 0;
    if (valid) {
        float4 pr = reinterpret_cast<const float4*>(priors)[p];
        px1 = pr.x - pr.z * 0.5f; py1 = pr.y - pr.w * 0.5f;
        px2 = pr.x + pr.z * 0.5f; py2 = pr.y + pr.w * 0.5f;
        parea = (px2 - px1) * (py2 - py1);
    }
    float ious[G];
    float best = -1.0f; int bidx = 0;
#pragma unroll
    for (int g = 0; g < G; ++g) {
        float iou = -1.0f;
        if (valid) {
            float4 gb = sg[g];
            float lx = fmaxf(gb.x, px1), ly = fmaxf(gb.y, py1);
            float rx = fminf(gb.z, px2), ry = fminf(gb.w, py2);
            float w = fmaxf(rx - lx, 0.0f), h = fmaxf(ry - ly, 0.0f);
            float inter = w * h;
            iou = inter / (sarea[g] + parea - inter);
        }
        ious[g] = iou;
        if (iou > best) { best = iou; bidx = g; }   // strict > keeps FIRST g
    }
    if (valid) {
        bt_ov[b * P + p] = best;
        bt_idx[b * P + p] = bidx;
    }

    // per-g argmax over this block's 256 priors
    int lane = threadIdx.x & 63, wid = threadIdx.x >> 6;
#pragma unroll
    for (int g = 0; g < G; ++g) {
        float v = ious[g];
        float m = v;
#pragma unroll
        for (int d = 32; d; d >>= 1) m = fmaxf(m, __shfl_xor(m, d));
        unsigned long long mask = __ballot(v == m);  // invalid lanes: v=-1 < m
        if (lane == 0) {
            unsigned long long pk = 0ull;
            if (m >= 0.0f) {
                int src = __ffsll(mask) - 1;          // lowest lane = smallest p
                int pw = p0 + wid * 64 + src;
                pk = ((unsigned long long)__float_as_uint(m) << 32)
                   | (unsigned)(0xFFFFFFFFu - (unsigned)pw);
            }
            swave[g][wid] = pk;
        }
    }
    __syncthreads();
    if (threadIdx.x < G) {
        int g = threadIdx.x;
        unsigned long long mx = swave[g][0];
        mx = swave[g][1] > mx ? swave[g][1] : mx;
        mx = swave[g][2] > mx ? swave[g][2] : mx;
        mx = swave[g][3] > mx ? swave[g][3] : mx;
        atomicMax(&bp_max[b * G + g], mx);
    }
}

// ---------------------------------------------------------------------------
// Kernel 2: main streaming kernel. Per (b,p): conf target (forced-prior
// override checked inline), box loss for positives, CE loss, mined value.
// conf staged global->reg (static 11x float4, MLP=11) -> LDS.
// NO global atomics: per-block partials stored to partial[b*PB+bx].
// ---------------------------------------------------------------------------
__global__ __launch_bounds__(256) void k_main(
    const float* __restrict__ loc_data, const float* __restrict__ conf_data,
    const float* __restrict__ priors, const float* __restrict__ gt,
    const int* __restrict__ labels,
    const float* __restrict__ bt_ov, const int* __restrict__ bt_idx,
    const unsigned long long* __restrict__ bp_max,
    float* __restrict__ mined,
    float4* __restrict__ partial) {
    int b = blockIdx.y;
    int p0 = blockIdx.x * 256;
    int p = p0 + threadIdx.x;
    __shared__ float sconf[256 * C];
    __shared__ int sforce[G];
    if (threadIdx.x < G)
        sforce[threadIdx.x] = (int)(0xFFFFFFFFu - (unsigned)bp_max[b * G + threadIdx.x]);
    int valid = min(256, P - p0);
    size_t gbase = ((size_t)b * P + p0) * C;
    int tot4 = (valid * C) >> 2;          // exact: 256*41 and 48*41 both %4==0
    const float4* g4 = reinterpret_cast<const float4*>(conf_data + gbase);
    float4* s4 = reinterpret_cast<float4*>(sconf);
    // register staging: all loads issued before any LDS write (MLP = 11)
    float4 r0, r1, r2, r3, r4, r5, r6, r7, r8, r9, r10;
#define LD(j, rj) { int i = threadIdx.x + (j) * 256; if (i < tot4) rj = g4[i]; }
#define ST(j, rj) { int i = threadIdx.x + (j) * 256; if (i < tot4) s4[i] = rj; }
    LD(0, r0) LD(1, r1) LD(2, r2) LD(3, r3) LD(4, r4) LD(5, r5)
    LD(6, r6) LD(7, r7) LD(8, r8) LD(9, r9) LD(10, r10)
    ST(0, r0) ST(1, r1) ST(2, r2) ST(3, r3) ST(4, r4) ST(5, r5)
    ST(6, r6) ST(7, r7) ST(8, r8) ST(9, r9) ST(10, r10)
#undef LD
#undef ST
    __syncthreads();

    float my_box = 0.0f, my_posc = 0.0f; int my_pos = 0;
    if (p < P) {
        float ov = bt_ov[b * P + p];
        int fidx = -1;
#pragma unroll
        for (int g = 0; g < G; ++g)
            if (p == sforce[g]) fidx = g;             // ascending g: LAST wins
        bool pos = false, neutral = false;
        int gidx = 0, cls = 0;
        float boxl = 0.0f;
        if (fidx >= 0)            { pos = true; gidx = fidx; }
        else if (ov >= POS_TH)    { pos = true; gidx = bt_idx[b * P + p]; }
        else if (ov >= NEG_TH)    { neutral = true; }
        if (pos) {
            cls = labels[b * G + gidx] + 1;
            float4 gb = reinterpret_cast<const float4*>(gt)[b * G + gidx];
            float4 pr = reinterpret_cast<const float4*>(priors)[p];
            float mcx = (gb.x + gb.z) * 0.5f, mcy = (gb.y + gb.w) * 0.5f;
            float tx = (mcx - pr.x) / (0.1f * pr.z);
            float ty = (mcy - pr.y) / (0.1f * pr.w);
            float tw = __logf(fmaxf((gb.z - gb.x) / pr.z, 1e-8f)) / 0.2f;
            float th = __logf(fmaxf((gb.w - gb.y) / pr.w, 1e-8f)) / 0.2f;
            float4 ld = reinterpret_cast<const float4*>(loc_data)[b * P + p];
            boxl = sl1(ld.x - tx) + sl1(ld.y - ty) + sl1(ld.z - tw) + sl1(ld.w - th);
        }
        const float* cv = &sconf[threadIdx.x * C];
        float mx = cv[0];
#pragma unroll
        for (int c = 1; c < C; ++c) mx = fmaxf(mx, cv[c]);
        float se = 0.0f;
#pragma unroll
        for (int c = 0; c < C; ++c) se += __expf(cv[c] - mx);
        float lse = mx + __logf(se);
        float lc = lse - cv[cls];          // >= 0 always (lse >= mx >= picked)
        mined[(size_t)b * P + p] = (pos || neutral) ? 0.0f : lc;
        my_pos = pos ? 1 : 0;
        my_box = boxl;
        my_posc = pos ? lc : 0.0f;
    }

#pragma unroll
    for (int d = 32; d; d >>= 1) {
        my_box  += __shfl_xor(my_box, d);
        my_posc += __shfl_xor(my_posc, d);
        my_pos  += __shfl_xor(my_pos, d);
    }
    __shared__ float rb[4], rc[4]; __shared__ int rp[4];
    int wid = threadIdx.x >> 6, lane = threadIdx.x & 63;
    if (lane == 0) { rb[wid] = my_box; rc[wid] = my_posc; rp[wid] = my_pos; }
    __syncthreads();
    if (threadIdx.x == 0) {
        float sb = rb[0] + rb[1] + rb[2] + rb[3];
        float sc = rc[0] + rc[1] + rc[2] + rc[3];
        int   sp = rp[0] + rp[1] + rp[2] + rp[3];
        partial[b * PB + blockIdx.x] = make_float4(sb, sc, (float)sp, 0.0f);
    }
}

// ---------------------------------------------------------------------------
// Kernel 3: per batch, sum of top-k of mined (k = min(3*npos_b, P-1)).
// npos_b recovered from partials (76 per batch). Exact k-th largest via
// 4-level radix select on float bits (all mined >= 0). Plain store of the
// per-batch negative sum (no contended atomics).
// ---------------------------------------------------------------------------
__global__ __launch_bounds__(1024) void k_topk(
    const float* __restrict__ mined, const float4* __restrict__ partial,
    float* __restrict__ neg_b) {
    int b = blockIdx.x;
    const float* mb = mined + (size_t)b * P;

    __shared__ int snp;
    if (threadIdx.x == 0) snp = 0;
    __syncthreads();
    if (threadIdx.x < PB) {
        int c = (int)partial[b * PB + threadIdx.x].z;
        if (c) atomicAdd(&snp, c);
    }
    __syncthreads();
    int np = snp;
    int k = 3 * np; if (k > P - 1) k = P - 1;
    if (k <= 0) { if (threadIdx.x == 0) neg_b[b] = 0.0f; return; }

    __shared__ unsigned hist[256];
    __shared__ unsigned sb[3];   // [0]=prefix, [1]=want, [2]=cnt_gt
    if (threadIdx.x == 0) { sb[0] = 0u; sb[1] = (unsigned)k; sb[2] = 0u; }
    __syncthreads();

#pragma unroll
    for (int level = 0; level < 4; ++level) {
        int shift = 24 - 8 * level;
        if (threadIdx.x < 256) hist[threadIdx.x] = 0u;
        __syncthreads();
        unsigned pref = sb[0];
        unsigned pmask = level ? (0xFFFFFFFFu << (shift + 8)) : 0u;
        for (int i = threadIdx.x; i < P; i += 1024) {
            unsigned v = __float_as_uint(mb[i]);
            if ((v & pmask) == pref)
                atomicAdd(&hist[(v >> shift) & 0xFFu], 1u);
        }
        __syncthreads();
        if (threadIdx.x == 0) {
            unsigned want = sb[1], cum = 0u; int bsel = 0;
            for (int bb = 255; bb >= 0; --bb) {
                unsigned h = hist[bb];
                if (cum + h >= want) { bsel = bb; break; }
                cum += h;
            }
            sb[0] = pref | ((unsigned)bsel << shift);
            sb[1] = want - cum;
            sb[2] += cum;
        }
        __syncthreads();
    }
    unsigned vk = sb[0];
    unsigned cnt_gt = sb[2];
    float vkf = __uint_as_float(vk);

    float ssum = 0.0f;
    for (int i = threadIdx.x; i < P; i += 1024) {
        float x = mb[i];
        if (__float_as_uint(x) > vk) ssum += x;
    }
#pragma unroll
    for (int d = 32; d; d >>= 1) ssum += __shfl_xor(ssum, d);
    __shared__ float rs[16];
    int wid = threadIdx.x >> 6, lane = threadIdx.x & 63;
    if (lane == 0) rs[wid] = ssum;
    __syncthreads();
    if (threadIdx.x == 0) {
        float tot = 0.0f;
#pragma unroll
        for (int w = 0; w < 16; ++w) tot += rs[w];
        tot += (float)(k - (int)cnt_gt) * vkf;
        neg_b[b] = tot;
    }
}

// ---------------------------------------------------------------------------
// Kernel 4: final reduction over 2432 block-partials + 32 neg sums -> loss.
// ---------------------------------------------------------------------------
__global__ __launch_bounds__(1024) void k_final(
    const float4* __restrict__ partial, const float* __restrict__ neg_b,
    float* __restrict__ out) {
    float sbx = 0.0f, sc = 0.0f, sp = 0.0f, sn = 0.0f;
    for (int i = threadIdx.x; i < B * PB; i += 1024) {
        float4 v = partial[i];
        sbx += v.x; sc += v.y; sp += v.z;
    }
    if (threadIdx.x < B) sn = neg_b[threadIdx.x];
#pragma unroll
    for (int d = 32; d; d >>= 1) {
        sbx += __shfl_xor(sbx, d);
        sc  += __shfl_xor(sc, d);
        sp  += __shfl_xor(sp, d);
        sn  += __shfl_xor(sn, d);
    }
    __shared__ float r[16][4];
    int wid = threadIdx.x >> 6, lane = threadIdx.x & 63;
    if (lane == 0) { r[wid][0] = sbx; r[wid][1] = sc; r[wid][2] = sp; r[wid][3] = sn; }
    __syncthreads();
    if (threadIdx.x == 0) {
        float tb = 0, tc = 0, tp = 0, tn = 0;
#pragma unroll
        for (int w = 0; w < 16; ++w) { tb += r[w][0]; tc += r[w][1]; tp += r[w][2]; tn += r[w][3]; }
        float np = fmaxf(tp, 1.0f);
        out[0] = tb / np * 1.5f + (tc + tn) / np * 6.5f;
    }
}

extern "C" void kernel_launch(void* const* d_in, const int* in_sizes, int n_in,
                              void* d_out, int out_size, void* d_ws, size_t ws_size,
                              hipStream_t stream) {
    const float* loc    = (const float*)d_in[0];
    const float* conf   = (const float*)d_in[1];
    const float* priors = (const float*)d_in[2];
    const float* gt     = (const float*)d_in[3];
    const int*   labels = (const int*)d_in[4];
    float* out = (float*)d_out;

    char* w = (char*)d_ws;
    float* bt_ov  = (float*)w;  w += sizeof(float) * B * P;
    int*   bt_idx = (int*)w;    w += sizeof(int)   * B * P;
    float* mined  = (float*)w;  w += sizeof(float) * B * P;
    unsigned long long* bp = (unsigned long long*)w; w += sizeof(unsigned long long) * B * G;
    float4* partial = (float4*)w; w += sizeof(float4) * B * PB;
    float* negb   = (float*)w;  w += sizeof(float) * B;

    // bp_max must be zero BEFORE k_match's atomicMax.
    hipMemsetAsync(bp, 0, sizeof(unsigned long long) * B * G, stream);

    dim3 gridP(PB, B);
    k_match<<<gridP, 256, 0, stream>>>(priors, gt, bt_ov, bt_idx, bp);
    k_main<<<gridP, 256, 0, stream>>>(loc, conf, priors, gt, labels,
                                      bt_ov, bt_idx, bp, mined, partial);
    k_topk<<<B, 1024, 0, stream>>>(mined, partial, negb);
    k_final<<<1, 1024, 0, stream>>>(partial, negb, out);
}

// Round 4
// 97.662 us; speedup vs baseline: 2.6809x; 1.4321x over previous
//
#include <hip/hip_runtime.h>

// Problem constants (from reference setup_inputs)
static constexpr int B = 32;
static constexpr int P = 19248;
static constexpr int G = 32;
static constexpr int C = 41;          // num classes
static constexpr float POS_TH = 0.5f;
static constexpr float NEG_TH = 0.4f;

static constexpr int PBM256 = (P + 255) / 256;   // 76  (k_match tiles)
static constexpr int TM = 128;                   // k_main block size
static constexpr int PBM = (P + TM - 1) / TM;    // 151 (k_main tiles)

__device__ __forceinline__ float sl1(float d) {
    d = fabsf(d);
    return d < 1.0f ? 0.5f * d * d : d - 0.5f;
}

// ---------------------------------------------------------------------------
// Kernel 1: per (b,g) best prior only (argmax IoU over p). Wave reduce +
// packed-u64 atomicMax ((iou_bits<<32)|(~p) -> higher IoU, then smaller p).
// 1024 distinct addresses, 76 blocks each -> low contention.
// ---------------------------------------------------------------------------
__global__ __launch_bounds__(256) void k_match(
    const float* __restrict__ priors, const float* __restrict__ gt,
    unsigned long long* __restrict__ bp_max) {
    int b = blockIdx.y;
    int p0 = blockIdx.x * 256;
    int p = p0 + threadIdx.x;
    __shared__ float4 sg[G];
    __shared__ float sarea[G];
    __shared__ unsigned long long swave[G][4];

    if (threadIdx.x < G) {
        float4 g4 = reinterpret_cast<const float4*>(gt)[b * G + threadIdx.x];
        sg[threadIdx.x] = g4;
        sarea[threadIdx.x] = (g4.z - g4.x) * (g4.w - g4.y);
    }
    __syncthreads();

    bool valid = (p < P);
    float px1 = 0, py1 = 0, px2 = 0, py2 = 0, parea = 0;
    if (valid) {
        float4 pr = reinterpret_cast<const float4*>(priors)[p];
        px1 = pr.x - pr.z * 0.5f; py1 = pr.y - pr.w * 0.5f;
        px2 = pr.x + pr.z * 0.5f; py2 = pr.y + pr.w * 0.5f;
        parea = (px2 - px1) * (py2 - py1);
    }
    int lane = threadIdx.x & 63, wid = threadIdx.x >> 6;
#pragma unroll
    for (int g = 0; g < G; ++g) {
        float iou = -1.0f;
        if (valid) {
            float4 gb = sg[g];
            float lx = fmaxf(gb.x, px1), ly = fmaxf(gb.y, py1);
            float rx = fminf(gb.z, px2), ry = fminf(gb.w, py2);
            float w = fmaxf(rx - lx, 0.0f), h = fmaxf(ry - ly, 0.0f);
            float inter = w * h;
            iou = inter / (sarea[g] + parea - inter);
        }
        float m = iou;
#pragma unroll
        for (int d = 32; d; d >>= 1) m = fmaxf(m, __shfl_xor(m, d));
        unsigned long long mask = __ballot(iou == m);
        if (lane == 0) {
            unsigned long long pk = 0ull;
            if (m >= 0.0f) {
                int src = __ffsll(mask) - 1;          // lowest lane = smallest p
                int pw = p0 + wid * 64 + src;
                pk = ((unsigned long long)__float_as_uint(m) << 32)
                   | (unsigned)(0xFFFFFFFFu - (unsigned)pw);
            }
            swave[g][wid] = pk;
        }
    }
    __syncthreads();
    if (threadIdx.x < G) {
        int g = threadIdx.x;
        unsigned long long mx = swave[g][0];
        mx = swave[g][1] > mx ? swave[g][1] : mx;
        mx = swave[g][2] > mx ? swave[g][2] : mx;
        mx = swave[g][3] > mx ? swave[g][3] : mx;
        atomicMax(&bp_max[b * G + g], mx);
    }
}

// ---------------------------------------------------------------------------
// Kernel 2: main streaming kernel (128 threads, 21 KB LDS -> 7 blocks/CU).
// Per (b,p): inline IoU argmax over G (replaces bt_ov/bt_idx round-trip),
// forced-prior override, box loss for positives, CE loss, mined value.
// conf staged global->reg (static float4, MLP) -> LDS. No global atomics.
// ---------------------------------------------------------------------------
__global__ __launch_bounds__(128) void k_main(
    const float* __restrict__ loc_data, const float* __restrict__ conf_data,
    const float* __restrict__ priors, const float* __restrict__ gt,
    const int* __restrict__ labels,
    const unsigned long long* __restrict__ bp_max,
    float* __restrict__ mined,
    float4* __restrict__ partial) {
    int b = blockIdx.y;
    int p0 = blockIdx.x * TM;
    int p = p0 + threadIdx.x;
    __shared__ float sconf[TM * C];
    __shared__ int sforce[G];
    __shared__ float4 sg[G];
    __shared__ float sarea[G];
    if (threadIdx.x < G) {
        sforce[threadIdx.x] = (int)(0xFFFFFFFFu - (unsigned)bp_max[b * G + threadIdx.x]);
        float4 g4 = reinterpret_cast<const float4*>(gt)[b * G + threadIdx.x];
        sg[threadIdx.x] = g4;
        sarea[threadIdx.x] = (g4.z - g4.x) * (g4.w - g4.y);
    }
    int valid = min(TM, P - p0);
    size_t gbase = ((size_t)b * P + p0) * C;
    int tot4 = (valid * C) >> 2;          // exact: 128*41 and 48*41 both %4==0
    const float4* g4p = reinterpret_cast<const float4*>(conf_data + gbase);
    float4* s4 = reinterpret_cast<float4*>(sconf);
    // register staging: all loads issued before any LDS write
    float4 r0, r1, r2, r3, r4, r5, r6, r7, r8, r9, r10;
#define LD(j, rj) { int i = threadIdx.x + (j) * TM; if (i < tot4) rj = g4p[i]; }
#define ST(j, rj) { int i = threadIdx.x + (j) * TM; if (i < tot4) s4[i] = rj; }
    LD(0, r0) LD(1, r1) LD(2, r2) LD(3, r3) LD(4, r4) LD(5, r5)
    LD(6, r6) LD(7, r7) LD(8, r8) LD(9, r9) LD(10, r10)
    ST(0, r0) ST(1, r1) ST(2, r2) ST(3, r3) ST(4, r4) ST(5, r5)
    ST(6, r6) ST(7, r7) ST(8, r8) ST(9, r9) ST(10, r10)
#undef LD
#undef ST
    __syncthreads();

    float my_box = 0.0f, my_posc = 0.0f; int my_pos = 0;
    if (p < P) {
        // inline best-truth: max/argmax IoU over G, first-max tie-break
        float4 pr = reinterpret_cast<const float4*>(priors)[p];
        float px1 = pr.x - pr.z * 0.5f, py1 = pr.y - pr.w * 0.5f;
        float px2 = pr.x + pr.z * 0.5f, py2 = pr.y + pr.w * 0.5f;
        float parea = (px2 - px1) * (py2 - py1);
        float ov = -1.0f; int bidx = 0;
#pragma unroll
        for (int g = 0; g < G; ++g) {
            float4 gb = sg[g];
            float lx = fmaxf(gb.x, px1), ly = fmaxf(gb.y, py1);
            float rx = fminf(gb.z, px2), ry = fminf(gb.w, py2);
            float w = fmaxf(rx - lx, 0.0f), h = fmaxf(ry - ly, 0.0f);
            float inter = w * h;
            float iou = inter / (sarea[g] + parea - inter);
            if (iou > ov) { ov = iou; bidx = g; }   // strict > keeps FIRST g
        }
        int fidx = -1;
#pragma unroll
        for (int g = 0; g < G; ++g)
            if (p == sforce[g]) fidx = g;             // ascending g: LAST wins
        bool pos = false, neutral = false;
        int gidx = 0, cls = 0;
        float boxl = 0.0f;
        if (fidx >= 0)            { pos = true; gidx = fidx; }
        else if (ov >= POS_TH)    { pos = true; gidx = bidx; }
        else if (ov >= NEG_TH)    { neutral = true; }
        if (pos) {
            cls = labels[b * G + gidx] + 1;
            float4 gb = sg[gidx];
            float mcx = (gb.x + gb.z) * 0.5f, mcy = (gb.y + gb.w) * 0.5f;
            float tx = (mcx - pr.x) / (0.1f * pr.z);
            float ty = (mcy - pr.y) / (0.1f * pr.w);
            float tw = __logf(fmaxf((gb.z - gb.x) / pr.z, 1e-8f)) / 0.2f;
            float th = __logf(fmaxf((gb.w - gb.y) / pr.w, 1e-8f)) / 0.2f;
            float4 ld = reinterpret_cast<const float4*>(loc_data)[b * P + p];
            boxl = sl1(ld.x - tx) + sl1(ld.y - ty) + sl1(ld.z - tw) + sl1(ld.w - th);
        }
        const float* cv = &sconf[threadIdx.x * C];
        float mx = cv[0];
#pragma unroll
        for (int c = 1; c < C; ++c) mx = fmaxf(mx, cv[c]);
        float se = 0.0f;
#pragma unroll
        for (int c = 0; c < C; ++c) se += __expf(cv[c] - mx);
        float lse = mx + __logf(se);
        float lc = lse - cv[cls];          // >= 0 always (lse >= mx >= picked)
        mined[(size_t)b * P + p] = (pos || neutral) ? 0.0f : lc;
        my_pos = pos ? 1 : 0;
        my_box = boxl;
        my_posc = pos ? lc : 0.0f;
    }

#pragma unroll
    for (int d = 32; d; d >>= 1) {
        my_box  += __shfl_xor(my_box, d);
        my_posc += __shfl_xor(my_posc, d);
        my_pos  += __shfl_xor(my_pos, d);
    }
    __shared__ float rb[2], rc[2]; __shared__ int rp[2];
    int wid = threadIdx.x >> 6, lane = threadIdx.x & 63;
    if (lane == 0) { rb[wid] = my_box; rc[wid] = my_posc; rp[wid] = my_pos; }
    __syncthreads();
    if (threadIdx.x == 0) {
        partial[b * PBM + blockIdx.x] =
            make_float4(rb[0] + rb[1], rc[0] + rc[1], (float)(rp[0] + rp[1]), 0.0f);
    }
}

// ---------------------------------------------------------------------------
// Kernel 3: per batch, sum of top-k of mined (k = min(3*npos_b, P-1)).
// 3-level radix select (11+11+10 bits, 2048-bin LDS hist) with PARALLEL
// suffix-scan selection (no serial thread-0 bin walk). All mined >= 0 so
// uint ordering == float ordering. Plain store of the per-batch neg sum.
// ---------------------------------------------------------------------------
__global__ __launch_bounds__(1024) void k_topk(
    const float* __restrict__ mined, const float4* __restrict__ partial,
    float* __restrict__ neg_b) {
    int b = blockIdx.x;
    const float* mb = mined + (size_t)b * P;
    int tid = threadIdx.x;
    int lane = tid & 63, wid = tid >> 6;

    __shared__ int snp;
    if (tid == 0) snp = 0;
    __syncthreads();
    if (tid < PBM) {
        int c = (int)partial[b * PBM + tid].z;
        if (c) atomicAdd(&snp, c);
    }
    __syncthreads();
    int k = 3 * snp; if (k > P - 1) k = P - 1;
    if (k <= 0) { if (tid == 0) neg_b[b] = 0.0f; return; }

    __shared__ unsigned hist[2048];
    __shared__ unsigned sel[3];     // [0]=prefix, [1]=want, [2]=cnt_gt
    __shared__ unsigned wtot[16];
    if (tid == 0) { sel[0] = 0u; sel[1] = (unsigned)k; sel[2] = 0u; }

    const int shifts[3] = {21, 10, 0};
    const int widths[3] = {11, 11, 10};
#pragma unroll
    for (int level = 0; level < 3; ++level) {
        int shift = shifts[level];
        unsigned bmask = (1u << widths[level]) - 1u;
        hist[tid] = 0u; hist[tid + 1024] = 0u;
        __syncthreads();
        unsigned pref = sel[0];
        unsigned pmask = level ? (0xFFFFFFFFu << (shift + widths[level])) : 0u;
        for (int i = tid; i < P; i += 1024) {
            unsigned v = __float_as_uint(mb[i]);
            if ((v & pmask) == pref)
                atomicAdd(&hist[(v >> shift) & bmask], 1u);
        }
        __syncthreads();
        // parallel suffix-scan selection over 2048 bins
        unsigned h0 = hist[2 * tid], h1 = hist[2 * tid + 1];
        unsigned x = h0 + h1;
#pragma unroll
        for (int d = 1; d < 64; d <<= 1) {
            unsigned t = __shfl_down(x, d);
            if (lane + d < 64) x += t;
        }
        if (lane == 0) wtot[wid] = x;
        __syncthreads();
        unsigned above = 0;
        for (int w2 = wid + 1; w2 < 16; ++w2) above += wtot[w2];
        // re-broadcast in-wave suffix including own pair
        unsigned sp = x + above;             // S(2t): suffix sum from bin 2t up
        unsigned s2 = sp - h0 - h1;          // S(2t+2)
        unsigned s1 = s2 + h1;               // S(2t+1)
        unsigned want = sel[1];
        __syncthreads();                     // everyone read want before writes
        if (s1 >= want && s2 < want) {       // bin 2t+1 is the crossing
            sel[0] = pref | (((2u * tid + 1u) & bmask) << shift);
            sel[1] = want - s2;
            sel[2] += s2;
        } else if (sp >= want && s1 < want) {// bin 2t is the crossing
            sel[0] = pref | (((2u * tid) & bmask) << shift);
            sel[1] = want - s1;
            sel[2] += s1;
        }
        __syncthreads();
    }
    unsigned vk = sel[0];
    unsigned cnt_gt = sel[2];
    float vkf = __uint_as_float(vk);

    float ssum = 0.0f;
    for (int i = tid; i < P; i += 1024) {
        float x = mb[i];
        if (__float_as_uint(x) > vk) ssum += x;
    }
#pragma unroll
    for (int d = 32; d; d >>= 1) ssum += __shfl_xor(ssum, d);
    __shared__ float rs[16];
    if (lane == 0) rs[wid] = ssum;
    __syncthreads();
    if (tid == 0) {
        float tot = 0.0f;
#pragma unroll
        for (int w = 0; w < 16; ++w) tot += rs[w];
        tot += (float)(k - (int)cnt_gt) * vkf;
        neg_b[b] = tot;
    }
}

// ---------------------------------------------------------------------------
// Kernel 4: final reduction over block-partials + 32 neg sums -> loss.
// ---------------------------------------------------------------------------
__global__ __launch_bounds__(1024) void k_final(
    const float4* __restrict__ partial, const float* __restrict__ neg_b,
    float* __restrict__ out) {
    float sbx = 0.0f, sc = 0.0f, sp = 0.0f, sn = 0.0f;
    for (int i = threadIdx.x; i < B * PBM; i += 1024) {
        float4 v = partial[i];
        sbx += v.x; sc += v.y; sp += v.z;
    }
    if (threadIdx.x < B) sn = neg_b[threadIdx.x];
#pragma unroll
    for (int d = 32; d; d >>= 1) {
        sbx += __shfl_xor(sbx, d);
        sc  += __shfl_xor(sc, d);
        sp  += __shfl_xor(sp, d);
        sn  += __shfl_xor(sn, d);
    }
    __shared__ float r[16][4];
    int wid = threadIdx.x >> 6, lane = threadIdx.x & 63;
    if (lane == 0) { r[wid][0] = sbx; r[wid][1] = sc; r[wid][2] = sp; r[wid][3] = sn; }
    __syncthreads();
    if (threadIdx.x == 0) {
        float tb = 0, tc = 0, tp = 0, tn = 0;
#pragma unroll
        for (int w = 0; w < 16; ++w) { tb += r[w][0]; tc += r[w][1]; tp += r[w][2]; tn += r[w][3]; }
        float np = fmaxf(tp, 1.0f);
        out[0] = tb / np * 1.5f + (tc + tn) / np * 6.5f;
    }
}

extern "C" void kernel_launch(void* const* d_in, const int* in_sizes, int n_in,
                              void* d_out, int out_size, void* d_ws, size_t ws_size,
                              hipStream_t stream) {
    const float* loc    = (const float*)d_in[0];
    const float* conf   = (const float*)d_in[1];
    const float* priors = (const float*)d_in[2];
    const float* gt     = (const float*)d_in[3];
    const int*   labels = (const int*)d_in[4];
    float* out = (float*)d_out;

    char* w = (char*)d_ws;
    float* mined  = (float*)w;  w += sizeof(float) * B * P;
    unsigned long long* bp = (unsigned long long*)w; w += sizeof(unsigned long long) * B * G;
    float4* partial = (float4*)w; w += sizeof(float4) * B * PBM;
    float* negb   = (float*)w;  w += sizeof(float) * B;

    // bp_max must be zero BEFORE k_match's atomicMax.
    hipMemsetAsync(bp, 0, sizeof(unsigned long long) * B * G, stream);

    k_match<<<dim3(PBM256, B), 256, 0, stream>>>(priors, gt, bp);
    k_main<<<dim3(PBM, B), TM, 0, stream>>>(loc, conf, priors, gt, labels,
                                            bp, mined, partial);
    k_topk<<<B, 1024, 0, stream>>>(mined, partial, negb);
    k_final<<<1, 1024, 0, stream>>>(partial, negb, out);
}

// Round 5
// 88.130 us; speedup vs baseline: 2.9709x; 1.1082x over previous
//
#include <hip/hip_runtime.h>

// Problem constants (from reference setup_inputs)
static constexpr int B = 32;
static constexpr int P = 19248;
static constexpr int G = 32;
static constexpr int C = 41;          // num classes
static constexpr float POS_TH = 0.5f;
static constexpr float NEG_TH = 0.4f;

static constexpr int TM = 128;                   // k_main block size
static constexpr int PBM = (P + TM - 1) / TM;    // 151 (k_main tiles)
static constexpr int NPART = 8;                  // k_match prior partitions
static constexpr int PPART = P / NPART;          // 2406 (exact: 19248 = 8*2406)

__device__ __forceinline__ float sl1(float d) {
    d = fabsf(d);
    return d < 1.0f ? 0.5f * d * d : d - 0.5f;
}

// ---------------------------------------------------------------------------
// Kernel 1: per (b,g) best prior, partitioned. Grid (NPART, B) x 1024 thr.
// Wave w handles g = w and g = w+16 over its prior part: per-lane running
// best (ascending p + strict > = first-max tie-break), then one packed-u64
// wave reduce ((iou_bits<<32)|~p -> higher IoU, then smaller p). Plain
// stores, no atomics, no init required. Also zeroes the topk done-counter.
// ---------------------------------------------------------------------------
__global__ __launch_bounds__(1024) void k_match(
    const float* __restrict__ priors, const float* __restrict__ gt,
    unsigned long long* __restrict__ bp_part, int* __restrict__ done) {
    int part = blockIdx.x, b = blockIdx.y;
    if (part == 0 && b == 0 && threadIdx.x == 0) *done = 0;
    int lane = threadIdx.x & 63, wid = threadIdx.x >> 6;
    int pbase = part * PPART;
#pragma unroll
    for (int gsub = 0; gsub < 2; ++gsub) {
        int g = wid + gsub * 16;
        float4 gb = reinterpret_cast<const float4*>(gt)[b * G + g]; // broadcast
        float ga = (gb.z - gb.x) * (gb.w - gb.y);
        float best = -1.0f; int bidx = 0;
        for (int i = lane; i < PPART; i += 64) {
            int p = pbase + i;
            float4 pr = reinterpret_cast<const float4*>(priors)[p];
            float px1 = pr.x - pr.z * 0.5f, py1 = pr.y - pr.w * 0.5f;
            float px2 = pr.x + pr.z * 0.5f, py2 = pr.y + pr.w * 0.5f;
            float parea = (px2 - px1) * (py2 - py1);
            float lx = fmaxf(gb.x, px1), ly = fmaxf(gb.y, py1);
            float rx = fminf(gb.z, px2), ry = fminf(gb.w, py2);
            float w = fmaxf(rx - lx, 0.0f), h = fmaxf(ry - ly, 0.0f);
            float inter = w * h;
            float iou = inter / (ga + parea - inter);
            if (iou > best) { best = iou; bidx = p; }  // ascending p: first max
        }
        // best >= 0 always (iou >= 0), so float bits are order-preserving
        unsigned long long pk =
            ((unsigned long long)__float_as_uint(best) << 32)
            | (unsigned)(0xFFFFFFFFu - (unsigned)bidx);
#pragma unroll
        for (int d = 32; d; d >>= 1) {
            unsigned long long o = __shfl_xor(pk, d);
            if (o > pk) pk = o;
        }
        if (lane == 0) bp_part[(part * B + b) * G + g] = pk;
    }
}

// ---------------------------------------------------------------------------
// Kernel 2: main streaming kernel (128 threads, 21 KB LDS -> 7 blocks/CU).
// Per (b,p): inline IoU argmax over G, forced-prior override (8-part max
// combine), box loss for positives, CE loss, mined value. conf staged
// global->reg (static float4, MLP=11) -> LDS. No global atomics.
// ---------------------------------------------------------------------------
__global__ __launch_bounds__(128) void k_main(
    const float* __restrict__ loc_data, const float* __restrict__ conf_data,
    const float* __restrict__ priors, const float* __restrict__ gt,
    const int* __restrict__ labels,
    const unsigned long long* __restrict__ bp_part,
    float* __restrict__ mined,
    float4* __restrict__ partial) {
    int b = blockIdx.y;
    int p0 = blockIdx.x * TM;
    int p = p0 + threadIdx.x;
    __shared__ float sconf[TM * C];
    __shared__ int sforce[G];
    __shared__ float4 sg[G];
    __shared__ float sarea[G];
    if (threadIdx.x < G) {
        unsigned long long mx = 0ull;
#pragma unroll
        for (int q = 0; q < NPART; ++q) {
            unsigned long long v = bp_part[(q * B + b) * G + threadIdx.x];
            mx = v > mx ? v : mx;
        }
        sforce[threadIdx.x] = (int)(0xFFFFFFFFu - (unsigned)mx);
        float4 g4 = reinterpret_cast<const float4*>(gt)[b * G + threadIdx.x];
        sg[threadIdx.x] = g4;
        sarea[threadIdx.x] = (g4.z - g4.x) * (g4.w - g4.y);
    }
    int valid = min(TM, P - p0);
    size_t gbase = ((size_t)b * P + p0) * C;
    int tot4 = (valid * C) >> 2;          // exact: 128*41 and 48*41 both %4==0
    const float4* g4p = reinterpret_cast<const float4*>(conf_data + gbase);
    float4* s4 = reinterpret_cast<float4*>(sconf);
    // register staging: all loads issued before any LDS write
    float4 r0, r1, r2, r3, r4, r5, r6, r7, r8, r9, r10;
#define LD(j, rj) { int i = threadIdx.x + (j) * TM; if (i < tot4) rj = g4p[i]; }
#define ST(j, rj) { int i = threadIdx.x + (j) * TM; if (i < tot4) s4[i] = rj; }
    LD(0, r0) LD(1, r1) LD(2, r2) LD(3, r3) LD(4, r4) LD(5, r5)
    LD(6, r6) LD(7, r7) LD(8, r8) LD(9, r9) LD(10, r10)
    ST(0, r0) ST(1, r1) ST(2, r2) ST(3, r3) ST(4, r4) ST(5, r5)
    ST(6, r6) ST(7, r7) ST(8, r8) ST(9, r9) ST(10, r10)
#undef LD
#undef ST
    __syncthreads();

    float my_box = 0.0f, my_posc = 0.0f; int my_pos = 0;
    if (p < P) {
        // inline best-truth: max/argmax IoU over G, first-max tie-break
        float4 pr = reinterpret_cast<const float4*>(priors)[p];
        float px1 = pr.x - pr.z * 0.5f, py1 = pr.y - pr.w * 0.5f;
        float px2 = pr.x + pr.z * 0.5f, py2 = pr.y + pr.w * 0.5f;
        float parea = (px2 - px1) * (py2 - py1);
        float ov = -1.0f; int bidx = 0;
#pragma unroll
        for (int g = 0; g < G; ++g) {
            float4 gb = sg[g];
            float lx = fmaxf(gb.x, px1), ly = fmaxf(gb.y, py1);
            float rx = fminf(gb.z, px2), ry = fminf(gb.w, py2);
            float w = fmaxf(rx - lx, 0.0f), h = fmaxf(ry - ly, 0.0f);
            float inter = w * h;
            float iou = inter / (sarea[g] + parea - inter);
            if (iou > ov) { ov = iou; bidx = g; }   // strict > keeps FIRST g
        }
        int fidx = -1;
#pragma unroll
        for (int g = 0; g < G; ++g)
            if (p == sforce[g]) fidx = g;             // ascending g: LAST wins
        bool pos = false, neutral = false;
        int gidx = 0, cls = 0;
        float boxl = 0.0f;
        if (fidx >= 0)            { pos = true; gidx = fidx; }
        else if (ov >= POS_TH)    { pos = true; gidx = bidx; }
        else if (ov >= NEG_TH)    { neutral = true; }
        if (pos) {
            cls = labels[b * G + gidx] + 1;
            float4 gb = sg[gidx];
            float mcx = (gb.x + gb.z) * 0.5f, mcy = (gb.y + gb.w) * 0.5f;
            float tx = (mcx - pr.x) / (0.1f * pr.z);
            float ty = (mcy - pr.y) / (0.1f * pr.w);
            float tw = __logf(fmaxf((gb.z - gb.x) / pr.z, 1e-8f)) / 0.2f;
            float th = __logf(fmaxf((gb.w - gb.y) / pr.w, 1e-8f)) / 0.2f;
            float4 ld = reinterpret_cast<const float4*>(loc_data)[b * P + p];
            boxl = sl1(ld.x - tx) + sl1(ld.y - ty) + sl1(ld.z - tw) + sl1(ld.w - th);
        }
        const float* cv = &sconf[threadIdx.x * C];
        float mx = cv[0];
#pragma unroll
        for (int c = 1; c < C; ++c) mx = fmaxf(mx, cv[c]);
        float se = 0.0f;
#pragma unroll
        for (int c = 0; c < C; ++c) se += __expf(cv[c] - mx);
        float lse = mx + __logf(se);
        float lc = lse - cv[cls];          // >= 0 always (lse >= mx >= picked)
        mined[(size_t)b * P + p] = (pos || neutral) ? 0.0f : lc;
        my_pos = pos ? 1 : 0;
        my_box = boxl;
        my_posc = pos ? lc : 0.0f;
    }

#pragma unroll
    for (int d = 32; d; d >>= 1) {
        my_box  += __shfl_xor(my_box, d);
        my_posc += __shfl_xor(my_posc, d);
        my_pos  += __shfl_xor(my_pos, d);
    }
    __shared__ float rb[2], rc[2]; __shared__ int rp[2];
    int wid = threadIdx.x >> 6, lane = threadIdx.x & 63;
    if (lane == 0) { rb[wid] = my_box; rc[wid] = my_posc; rp[wid] = my_pos; }
    __syncthreads();
    if (threadIdx.x == 0) {
        partial[b * PBM + blockIdx.x] =
            make_float4(rb[0] + rb[1], rc[0] + rc[1], (float)(rp[0] + rp[1]), 0.0f);
    }
}

// ---------------------------------------------------------------------------
// Kernel 3: per batch, sum of top-k of mined (k = min(3*npos_b, P-1)) via
// 3-level radix select (11+11+10 bits, 2048-bin hist, parallel suffix-scan
// selection). The LAST block (device done-counter, split-K pattern) also
// performs the final reduction of partials + neg sums -> scalar loss.
// ---------------------------------------------------------------------------
__global__ __launch_bounds__(1024) void k_topk(
    const float* __restrict__ mined, const float4* __restrict__ partial,
    float* __restrict__ neg_b, int* __restrict__ done,
    float* __restrict__ out) {
    int b = blockIdx.x;
    const float* mb = mined + (size_t)b * P;
    int tid = threadIdx.x;
    int lane = tid & 63, wid = tid >> 6;

    __shared__ int snp;
    if (tid == 0) snp = 0;
    __syncthreads();
    if (tid < PBM) {
        int c = (int)partial[b * PBM + tid].z;
        if (c) atomicAdd(&snp, c);
    }
    __syncthreads();
    int k = 3 * snp; if (k > P - 1) k = P - 1;

    float negval = 0.0f;                 // valid on tid 0 after the branch
    if (k > 0) {                         // block-uniform branch (barriers ok)
        __shared__ unsigned hist[2048];
        __shared__ unsigned sel[3];      // [0]=prefix, [1]=want, [2]=cnt_gt
        __shared__ unsigned wtot[16];
        if (tid == 0) { sel[0] = 0u; sel[1] = (unsigned)k; sel[2] = 0u; }

        const int shifts[3] = {21, 10, 0};
        const int widths[3] = {11, 11, 10};
#pragma unroll
        for (int level = 0; level < 3; ++level) {
            int shift = shifts[level];
            unsigned bmask = (1u << widths[level]) - 1u;
            hist[tid] = 0u; hist[tid + 1024] = 0u;
            __syncthreads();
            unsigned pref = sel[0];
            unsigned pmask = level ? (0xFFFFFFFFu << (shift + widths[level])) : 0u;
            for (int i = tid; i < P; i += 1024) {
                unsigned v = __float_as_uint(mb[i]);
                if ((v & pmask) == pref)
                    atomicAdd(&hist[(v >> shift) & bmask], 1u);
            }
            __syncthreads();
            // parallel suffix-scan selection over 2048 bins
            unsigned h0 = hist[2 * tid], h1 = hist[2 * tid + 1];
            unsigned x = h0 + h1;
#pragma unroll
            for (int d = 1; d < 64; d <<= 1) {
                unsigned t = __shfl_down(x, d);
                if (lane + d < 64) x += t;
            }
            if (lane == 0) wtot[wid] = x;
            __syncthreads();
            unsigned above = 0;
            for (int w2 = wid + 1; w2 < 16; ++w2) above += wtot[w2];
            unsigned sp = x + above;             // S(2t)
            unsigned s2 = sp - h0 - h1;          // S(2t+2)
            unsigned s1 = s2 + h1;               // S(2t+1)
            unsigned want = sel[1];
            __syncthreads();                     // all read want before writes
            if (s1 >= want && s2 < want) {       // bin 2t+1 crosses
                sel[0] = pref | (((2u * tid + 1u) & bmask) << shift);
                sel[1] = want - s2;
                sel[2] += s2;
            } else if (sp >= want && s1 < want) {// bin 2t crosses
                sel[0] = pref | (((2u * tid) & bmask) << shift);
                sel[1] = want - s1;
                sel[2] += s1;
            }
            __syncthreads();
        }
        unsigned vk = sel[0];
        unsigned cnt_gt = sel[2];
        float vkf = __uint_as_float(vk);

        float ssum = 0.0f;
        for (int i = tid; i < P; i += 1024) {
            float x = mb[i];
            if (__float_as_uint(x) > vk) ssum += x;
        }
#pragma unroll
        for (int d = 32; d; d >>= 1) ssum += __shfl_xor(ssum, d);
        __shared__ float rs[16];
        if (lane == 0) rs[wid] = ssum;
        __syncthreads();
        if (tid == 0) {
            float tot = 0.0f;
#pragma unroll
            for (int w = 0; w < 16; ++w) tot += rs[w];
            negval = tot + (float)(k - (int)cnt_gt) * vkf;
        }
    }

    // completion protocol: store my batch's neg sum, last block finalizes
    __shared__ bool islast;
    if (tid == 0) {
        neg_b[b] = negval;
        __threadfence();                       // release neg_b
        int old = atomicAdd(done, 1);
        islast = (old == B - 1);
    }
    __syncthreads();
    if (islast) {
        __threadfence();                       // acquire other blocks' neg_b
        float sbx = 0.0f, sc = 0.0f, sp2 = 0.0f, sn = 0.0f;
        for (int i = tid; i < B * PBM; i += 1024) {
            float4 v = partial[i];
            sbx += v.x; sc += v.y; sp2 += v.z;
        }
        if (tid < B) sn = neg_b[tid];
#pragma unroll
        for (int d = 32; d; d >>= 1) {
            sbx += __shfl_xor(sbx, d);
            sc  += __shfl_xor(sc, d);
            sp2 += __shfl_xor(sp2, d);
            sn  += __shfl_xor(sn, d);
        }
        __shared__ float r[16][4];
        if (lane == 0) { r[wid][0] = sbx; r[wid][1] = sc; r[wid][2] = sp2; r[wid][3] = sn; }
        __syncthreads();
        if (tid == 0) {
            float tb = 0, tc = 0, tp = 0, tn = 0;
#pragma unroll
            for (int w = 0; w < 16; ++w) {
                tb += r[w][0]; tc += r[w][1]; tp += r[w][2]; tn += r[w][3];
            }
            float np = fmaxf(tp, 1.0f);
            out[0] = tb / np * 1.5f + (tc + tn) / np * 6.5f;
        }
    }
}

extern "C" void kernel_launch(void* const* d_in, const int* in_sizes, int n_in,
                              void* d_out, int out_size, void* d_ws, size_t ws_size,
                              hipStream_t stream) {
    const float* loc    = (const float*)d_in[0];
    const float* conf   = (const float*)d_in[1];
    const float* priors = (const float*)d_in[2];
    const float* gt     = (const float*)d_in[3];
    const int*   labels = (const int*)d_in[4];
    float* out = (float*)d_out;

    char* w = (char*)d_ws;
    float4* partial = (float4*)w;                      w += sizeof(float4) * B * PBM;
    float* mined  = (float*)w;                         w += sizeof(float) * B * P;
    unsigned long long* bp_part = (unsigned long long*)w;
    w += sizeof(unsigned long long) * NPART * B * G;
    float* negb   = (float*)w;                         w += sizeof(float) * B;
    int*   done   = (int*)w;                           w += sizeof(int);

    // 3 graph nodes; bp_part needs no init (plain stores), done zeroed in k_match
    k_match<<<dim3(NPART, B), 1024, 0, stream>>>(priors, gt, bp_part, done);
    k_main<<<dim3(PBM, B), TM, 0, stream>>>(loc, conf, priors, gt, labels,
                                            bp_part, mined, partial);
    k_topk<<<B, 1024, 0, stream>>>(mined, partial, negb, done, out);
}